// Round 6
// baseline (9431.346 us; speedup 1.0000x reference)
//
#include <hip/hip_runtime.h>
#include <stdint.h>

#define B_ 64
#define T_ 2048
#define I_ 512
#define H_ 512
#define NG 4     // batch groups (16 rows each)
#define WPG 32   // WGs per group (64 gate-cols each)

typedef short bf16x8 __attribute__((ext_vector_type(8)));
typedef float f32x4 __attribute__((ext_vector_type(4)));

__device__ __forceinline__ unsigned short f2bf(float f) {
  union { float f; unsigned u; } x; x.f = f;
  unsigned r = x.u + 0x7fffu + ((x.u >> 16) & 1u);
  return (unsigned short)(r >> 16);
}
__device__ __forceinline__ float sigm(float x) { return 1.0f / (1.0f + __expf(-x)); }
__device__ __forceinline__ float tanhfast(float x) { return 1.0f - 2.0f / (__expf(2.0f * x) + 1.0f); }

// Kernel 1: zero step counters + convert inputs (B,T,I) f32 -> (T,B,I) bf16
__global__ void prep_kernel(const float* __restrict__ in, unsigned short* __restrict__ xbf,
                            unsigned int* __restrict__ ctr) {
  int t = blockIdx.x;
  int tid = threadIdx.x;
  // ctr layout: slot (t*NG+bg)*16 dwords; 2049 steps x 64 dwords
  for (int i = tid; i < 64; i += 256) ctr[t * 64 + i] = 0u;
  if (t == 0) for (int i = tid; i < 64; i += 256) ctr[2048 * 64 + i] = 0u;
  const int slab = B_ * I_;  // 32768
  for (int idx = tid * 4; idx < slab; idx += 256 * 4) {
    int b = idx >> 9;
    int i = idx & 511;
    const float4 v = *reinterpret_cast<const float4*>(in + ((size_t)b * T_ + t) * I_ + i);
    ushort4 o;
    o.x = f2bf(v.x); o.y = f2bf(v.y); o.z = f2bf(v.z); o.w = f2bf(v.w);
    *reinterpret_cast<ushort4*>(xbf + (size_t)t * slab + idx) = o;
  }
}

// 16 dwordx4 fragment loads, byte offsets kk*64
#define APPLY16(M) M(0,"0") M(1,"64") M(2,"128") M(3,"192") M(4,"256") M(5,"320") \
  M(6,"384") M(7,"448") M(8,"512") M(9,"576") M(10,"640") M(11,"704") \
  M(12,"768") M(13,"832") M(14,"896") M(15,"960")

// Persistent LSTM: 128 WGs = 4 batch-groups (16 rows) x 32 col-slices (64 gate-cols:
// 16 cols of each gate => N-tile q == gate q => i,f,g,o for one (row,col) live in the
// SAME lane across acc[0..3]: no LDS remap, no __syncthreads, activations in-register.
// Sync: per-(t,group) atomic counter; poll runs with (nearly) empty vmem queue;
// counted vmcnt(16) separates h-arrival from the x(t+1) prefetch behind it.
// R6 fix: h published via global_store_short sc0 sc1 (write-through to coherence
// point) — R5's plain stores stayed in the producer XCD's L2 => stale h reads.
__global__ __launch_bounds__(64, 1) void lstm_kernel(
    const float* __restrict__ Wi, const float* __restrict__ bi,
    const float* __restrict__ Wh, const float* __restrict__ bh,
    const unsigned short* __restrict__ xbf,
    unsigned short* __restrict__ hbuf,
    unsigned int* ctr,
    float* __restrict__ out, float* __restrict__ hT)
{
  const int wg = blockIdx.x;   // 0..127
  const int bg = wg >> 5;      // batch group 0..3
  const int gc = wg & 31;      // col-slice 0..31
  const int lane = threadIdx.x;

  extern __shared__ char lds[];
  short* Wp = (short*)lds;     // 32kk x 4tile x 64lane x 8 = 128KB

  // ---- pack weight slice: lane owns col n=lane: gate q=lane>>4, j=lane&15
  {
    const int q = lane >> 4, j = lane & 15;
    const int col = (q << 9) + (gc << 4) + j;
    for (int kf = 0; kf < 512; ++kf) {
      float v = Wi[(size_t)kf * 2048 + col];
      const int kk = kf >> 5;
      const int lp = (((kf & 31) >> 3) << 4) + j;
      Wp[((((kk << 2) + q) << 6) + lp) * 8 + (kf & 7)] = (short)f2bf(v);
    }
    for (int kf = 512; kf < 1024; ++kf) {
      float v = Wh[(size_t)(kf - 512) * 2048 + col];
      const int kk = kf >> 5;
      const int lp = (((kf & 31) >> 3) << 4) + j;
      Wp[((((kk << 2) + q) << 6) + lp) * 8 + (kf & 7)] = (short)f2bf(v);
    }
  }
  const int jj = lane & 15;
  float rb[4];
#pragma unroll
  for (int q = 0; q < 4; ++q) {
    const int col = (q << 9) + (gc << 4) + jj;
    rb[q] = bi[col] + bh[col];
  }

  const int bbase = bg << 4;
  const size_t arow = ((size_t)(bbase + jj)) * 512 + ((lane >> 4) << 3);
  const short* wl = Wp + (lane << 3);
  const int hcol = (gc << 4) + jj;              // this lane's h/out column
  const int rowb = bbase + ((lane >> 4) << 2);  // first of 4 owned rows

  float c[4] = {0.f, 0.f, 0.f, 0.f};

  bf16x8 xa[16];
  bf16x8 ha[16];

#define LDX(i, OFF) asm volatile("global_load_dwordx4 %0, %1, off offset:" OFF \
    : "=v"(xa[i]) : "v"(xsrc) : "memory");
#define LDH(i, OFF) asm volatile("global_load_dwordx4 %0, %1, off offset:" OFF " sc0 sc1" \
    : "=v"(ha[i]) : "v"(hsrc) : "memory");

  // ---- prologue: x(0)
  {
    const unsigned short* xsrc = xbf + arow;
    APPLY16(LDX)
  }
  asm volatile("s_waitcnt vmcnt(0)" ::: "memory");
  __builtin_amdgcn_sched_barrier(0);

  for (int t = 0; t < T_; ++t) {
    f32x4 acc[4];
#pragma unroll
    for (int q = 0; q < 4; ++q) acc[q] = (f32x4){rb[q], rb[q], rb[q], rb[q]};

    if (t > 0) {
      // ---- poll (vmem queue near-empty: only last iter's o_t stores drain once)
      while (__hip_atomic_load(ctr + ((size_t)t * NG + bg) * 16,
                               __ATOMIC_RELAXED, __HIP_MEMORY_SCOPE_AGENT) < WPG) {}
      asm volatile("" ::: "memory");
      // ---- issue h loads immediately; they fly under the x-MFMAs below
      const unsigned short* hsrc = hbuf + (size_t)(t & 1) * (B_ * H_) + arow;
      APPLY16(LDH)
      __builtin_amdgcn_sched_barrier(0);
    }

    // ---- x-phase MFMA (xa prefetched last iter, already drained)
#pragma unroll
    for (int kk = 0; kk < 16; ++kk) {
      const short* wk = wl + (kk << 11);
#pragma unroll
      for (int q = 0; q < 4; ++q) {
        bf16x8 w = *reinterpret_cast<const bf16x8*>(wk + (q << 9));
        acc[q] = __builtin_amdgcn_mfma_f32_16x16x32_bf16(xa[kk], w, acc[q], 0, 0, 0);
      }
    }
    __builtin_amdgcn_sched_barrier(0);

    // ---- prefetch x(t+1) BEHIND the h loads
    {
      const int tn = (t + 1 < T_) ? t + 1 : t;
      const unsigned short* xsrc = xbf + (size_t)tn * (B_ * I_) + arow;
      APPLY16(LDX)
    }

    if (t > 0) {
      // in-order vmcnt retirement: <=16 outstanding => the 16 h loads are done
      asm volatile("s_waitcnt vmcnt(16)" ::: "memory");
      __builtin_amdgcn_sched_barrier(0);
#pragma unroll
      for (int kk = 0; kk < 16; ++kk) {
        const short* wk = wl + ((kk + 16) << 11);
#pragma unroll
        for (int q = 0; q < 4; ++q) {
          bf16x8 w = *reinterpret_cast<const bf16x8*>(wk + (q << 9));
          acc[q] = __builtin_amdgcn_mfma_f32_16x16x32_bf16(ha[kk], w, acc[q], 0, 0, 0);
        }
      }
    }

    // ---- activations fully in-register: lane owns rows rowb..rowb+3, col hcol
    unsigned short* hwb = hbuf + (size_t)((t + 1) & 1) * (B_ * H_);
    float osave[4];
#pragma unroll
    for (int r = 0; r < 4; ++r) {
      float gi = acc[0][r], gf = acc[1][r], gg = acc[2][r], go = acc[3][r];
      float ot = sigm(go);
      c[r] = sigm(gf) * c[r] + sigm(gi) * tanhfast(gg);
      float h = ot * tanhfast(c[r]);
      osave[r] = ot;
      // write-through to coherence point so other XCDs' sc0sc1 loads see it
      unsigned int hd = (unsigned int)f2bf(h);
      const unsigned short* hp = hwb + (size_t)(rowb + r) * H_ + hcol;
      asm volatile("global_store_short %0, %1, off sc0 sc1" :: "v"(hp), "v"(hd) : "memory");
    }
    if (t == T_ - 1) {
#pragma unroll
      for (int r = 0; r < 4; ++r) {
        float ot = osave[r];
        float h = ot * tanhfast(c[r]);
        hT[(size_t)(rowb + r) * H_ + hcol] = h;
      }
    }

    // ---- drain h-stores (+ x prefetch, long flown), then signal
    asm volatile("s_waitcnt vmcnt(0)" ::: "memory");
    __builtin_amdgcn_sched_barrier(0);
    if (lane == 0)
      __hip_atomic_fetch_add(ctr + ((size_t)(t + 1) * NG + bg) * 16, 1u,
                             __ATOMIC_RELAXED, __HIP_MEMORY_SCOPE_AGENT);

    // ---- o_t outputs off the critical path
#pragma unroll
    for (int r = 0; r < 4; ++r)
      out[((size_t)(rowb + r) * T_ + t) * H_ + hcol] = osave[r];
  }
#undef LDX
#undef LDH
}

extern "C" void kernel_launch(void* const* d_in, const int* in_sizes, int n_in,
                              void* d_out, int out_size, void* d_ws, size_t ws_size,
                              hipStream_t stream) {
  const float* inputs = (const float*)d_in[0];
  const float* Wi = (const float*)d_in[1];
  const float* bi = (const float*)d_in[2];
  const float* Wh = (const float*)d_in[3];
  const float* bh = (const float*)d_in[4];
  float* out = (float*)d_out;
  float* hT = out + (size_t)B_ * T_ * H_;

  // workspace: [ctr 2049*256B = 524544][hbuf 2x64KB = 131072][xbf 128MB]
  unsigned int* ctr = (unsigned int*)d_ws;
  unsigned short* hbuf = (unsigned short*)((char*)d_ws + 524544);
  unsigned short* xbf = (unsigned short*)((char*)d_ws + 524544 + 131072);

  (void)hipFuncSetAttribute((const void*)lstm_kernel,
                            hipFuncAttributeMaxDynamicSharedMemorySize, 131072);

  prep_kernel<<<dim3(T_), dim3(256), 0, stream>>>(inputs, xbf, ctr);
  lstm_kernel<<<dim3(128), dim3(64), 131072, stream>>>(Wi, bi, Wh, bh, xbf, hbuf, ctr, out, hT);
}

// Round 7
// 7109.404 us; speedup vs baseline: 1.3266x; 1.3266x over previous
//
#include <hip/hip_runtime.h>
#include <stdint.h>

#define B_ 64
#define T_ 2048
#define I_ 512
#define H_ 512
#define NG 4     // batch groups (16 rows each)
#define WPG 64   // WGs per group (32 gate-cols each)

typedef short bf16x8 __attribute__((ext_vector_type(8)));
typedef float f32x4 __attribute__((ext_vector_type(4)));

__device__ __forceinline__ unsigned short f2bf(float f) {
  union { float f; unsigned u; } x; x.f = f;
  unsigned r = x.u + 0x7fffu + ((x.u >> 16) & 1u);
  return (unsigned short)(r >> 16);
}
__device__ __forceinline__ float sigm(float x) { return 1.0f / (1.0f + __expf(-x)); }
__device__ __forceinline__ float tanhfast(float x) { return 1.0f - 2.0f / (__expf(2.0f * x) + 1.0f); }

// Kernel 1: zero step counters + convert inputs (B,T,I) f32 -> (T,B,I) bf16
__global__ void prep_kernel(const float* __restrict__ in, unsigned short* __restrict__ xbf,
                            unsigned int* __restrict__ ctr) {
  int t = blockIdx.x;
  int tid = threadIdx.x;
  // ctr layout: slot (t*NG+bg)*16 dwords; 2049 steps x 64 dwords
  for (int i = tid; i < 64; i += 256) ctr[t * 64 + i] = 0u;
  if (t == 0) for (int i = tid; i < 64; i += 256) ctr[2048 * 64 + i] = 0u;
  const int slab = B_ * I_;  // 32768
  for (int idx = tid * 4; idx < slab; idx += 256 * 4) {
    int b = idx >> 9;
    int i = idx & 511;
    const float4 v = *reinterpret_cast<const float4*>(in + ((size_t)b * T_ + t) * I_ + i);
    ushort4 o;
    o.x = f2bf(v.x); o.y = f2bf(v.y); o.z = f2bf(v.z); o.w = f2bf(v.w);
    *reinterpret_cast<ushort4*>(xbf + (size_t)t * slab + idx) = o;
  }
}

// 16 dwordx4 fragment loads, byte offsets kk*64
#define APPLY16(M) M(0,"0") M(1,"64") M(2,"128") M(3,"192") M(4,"256") M(5,"320") \
  M(6,"384") M(7,"448") M(8,"512") M(9,"576") M(10,"640") M(11,"704") \
  M(12,"768") M(13,"832") M(14,"896") M(15,"960")

// Persistent LSTM: 256 WGs = 4 batch-groups (16 rows) x 64 col-slices (32 gate-cols).
// R7: WEIGHTS REGISTER-RESIDENT — packed to LDS once (verified R4 path), then 64
// bf16x8 fragments (256 VGPR) are ds_read into registers; the steady-state K-loops
// are pure register MFMA (no per-MFMA LDS latency, which dominated R4/R6).
// Sync: per-(t,group) atomic counter; poll runs with near-empty vmem queue; h loads
// (sc0sc1) fly under x-MFMA; counted vmcnt(16) splits h-arrival from x(t+1) prefetch;
// h published write-through (sc0sc1) before the counter signal.
__global__ __launch_bounds__(64, 1) void lstm_kernel(
    const float* __restrict__ Wi, const float* __restrict__ bi,
    const float* __restrict__ Wh, const float* __restrict__ bh,
    const unsigned short* __restrict__ xbf,
    unsigned short* __restrict__ hbuf,
    unsigned int* ctr,
    float* __restrict__ out, float* __restrict__ hT)
{
  const int wg = blockIdx.x;   // 0..255
  const int bg = wg >> 6;      // batch group 0..3
  const int gc = wg & 63;      // col-slice 0..63
  const int lane = threadIdx.x;

  extern __shared__ char lds[];
  short* Wp = (short*)lds;               // 32kk x 2tile x 64lane x 8 = 64KB (prologue only)
  float* gates = (float*)(lds + 65536);  // 16 x 32 f32 = 2KB

  // ---- pack weight slice into LDS as B fragments (R4-verified layout)
  {
    const int n = lane & 31;                                   // gate-col index 0..31
    const int col = ((n >> 3) << 9) + (gc << 3) + (n & 7);     // q*512 + gc*8 + j
    for (int kf = (lane >> 5); kf < 1024; kf += 2) {
      float v = (kf < 512) ? Wi[(size_t)kf * 2048 + col]
                           : Wh[(size_t)(kf - 512) * 2048 + col];
      int kk = kf >> 5;
      int lp = (((kf & 31) >> 3) << 4) + (n & 15);             // B-frag lane
      int tl = n >> 4;                                          // N-tile
      Wp[((((kk << 1) + tl) << 6) + lp) * 8 + (kf & 7)] = (short)f2bf(v);
    }
  }
  const int n0 = lane & 15;
  const int col0 = ((n0 >> 3) << 9) + (gc << 3) + (n0 & 7);
  const int n1 = n0 + 16;
  const int col1 = ((n1 >> 3) << 9) + (gc << 3) + (n1 & 7);
  const float rb0 = bi[col0] + bh[col0];
  const float rb1 = bi[col1] + bh[col1];
  __syncthreads();

  // ---- hoist all 64 weight fragments into registers (one-time)
  const short* wl = Wp + (lane << 3);
  bf16x8 wreg[64];   // fragment f = kkAll*2 + tl, kkAll 0..31 (0-15 = Wi, 16-31 = Wh)
#pragma unroll
  for (int f = 0; f < 64; ++f)
    wreg[f] = *reinterpret_cast<const bf16x8*>(wl + (f << 9));

  const int bbase = bg << 4;
  const size_t arow = ((size_t)(bbase + (lane & 15))) * 512 + ((lane >> 4) << 3);
  const int jc = gc << 3;
  const int b_l = lane >> 2;           // local batch row for activation (0..15)
  const int j0 = (lane & 3) << 1;      // h-col pair within slice
  const int brow = bbase + b_l;

  float c0 = 0.f, c1 = 0.f;

  bf16x8 xa[16];
  bf16x8 ha[16];

#define LDX(i, OFF) asm volatile("global_load_dwordx4 %0, %1, off offset:" OFF \
    : "=v"(xa[i]) : "v"(xsrc) : "memory");
#define LDH(i, OFF) asm volatile("global_load_dwordx4 %0, %1, off offset:" OFF " sc0 sc1" \
    : "=v"(ha[i]) : "v"(hsrc) : "memory");

  // ---- prologue: x(0)
  {
    const unsigned short* xsrc = xbf + arow;
    APPLY16(LDX)
  }
  asm volatile("s_waitcnt vmcnt(0)" ::: "memory");
  __builtin_amdgcn_sched_barrier(0);

  for (int t = 0; t < T_; ++t) {
    f32x4 acc0 = {rb0, rb0, rb0, rb0};
    f32x4 acc1 = {rb1, rb1, rb1, rb1};

    if (t > 0) {
      // ---- poll (queue holds only last iter's o_t stores, L2-acked quickly)
      while (__hip_atomic_load(ctr + ((size_t)t * NG + bg) * 16,
                               __ATOMIC_RELAXED, __HIP_MEMORY_SCOPE_AGENT) < WPG) {}
      asm volatile("" ::: "memory");
      // ---- issue h loads immediately; they fly under the x-MFMAs below
      const unsigned short* hsrc = hbuf + (size_t)(t & 1) * (B_ * H_) + arow;
      APPLY16(LDH)
      __builtin_amdgcn_sched_barrier(0);
    }

    // ---- x-phase MFMA: pure registers (xa prefetched, wreg resident)
#pragma unroll
    for (int kk = 0; kk < 16; ++kk) {
      acc0 = __builtin_amdgcn_mfma_f32_16x16x32_bf16(xa[kk], wreg[2 * kk],     acc0, 0, 0, 0);
      acc1 = __builtin_amdgcn_mfma_f32_16x16x32_bf16(xa[kk], wreg[2 * kk + 1], acc1, 0, 0, 0);
    }
    __builtin_amdgcn_sched_barrier(0);

    // ---- prefetch x(t+1) BEHIND the h loads
    {
      const int tn = (t + 1 < T_) ? t + 1 : t;
      const unsigned short* xsrc = xbf + (size_t)tn * (B_ * I_) + arow;
      APPLY16(LDX)
    }

    if (t > 0) {
      // in-order vmcnt retirement: <=16 outstanding => the 16 h loads are done
      asm volatile("s_waitcnt vmcnt(16)" ::: "memory");
      __builtin_amdgcn_sched_barrier(0);
#pragma unroll
      for (int kk = 0; kk < 16; ++kk) {
        acc0 = __builtin_amdgcn_mfma_f32_16x16x32_bf16(ha[kk], wreg[32 + 2 * kk],     acc0, 0, 0, 0);
        acc1 = __builtin_amdgcn_mfma_f32_16x16x32_bf16(ha[kk], wreg[32 + 2 * kk + 1], acc1, 0, 0, 0);
      }
    }

    // C/D layout: col = lane&15, row = (lane>>4)*4 + r  -> remap through LDS
    {
      const int cc = lane & 15;
      const int rb = (lane >> 4) << 2;
#pragma unroll
      for (int r = 0; r < 4; ++r) {
        gates[(rb + r) * 32 + cc] = acc0[r];
        gates[(rb + r) * 32 + 16 + cc] = acc1[r];
      }
    }
    __syncthreads();
    const float* grow = gates + b_l * 32;
    float gi0 = grow[j0],      gi1 = grow[j0 + 1];
    float gf0 = grow[8 + j0],  gf1 = grow[9 + j0];
    float gg0 = grow[16 + j0], gg1 = grow[17 + j0];
    float go0 = grow[24 + j0], go1 = grow[25 + j0];
    __syncthreads();  // cheap: single wave
    float o0 = sigm(go0), o1 = sigm(go1);
    c0 = sigm(gf0) * c0 + sigm(gi0) * tanhfast(gg0);
    c1 = sigm(gf1) * c1 + sigm(gi1) * tanhfast(gg1);
    float h0 = o0 * tanhfast(c0);
    float h1 = o1 * tanhfast(c1);

    // ---- publish h (write-through to coherence point), then signal
    unsigned int hpack = (unsigned int)f2bf(h0) | ((unsigned int)f2bf(h1) << 16);
    unsigned int* hw = (unsigned int*)(hbuf + (size_t)((t + 1) & 1) * (B_ * H_) + (size_t)brow * H_ + jc + j0);
    __hip_atomic_store(hw, hpack, __ATOMIC_RELAXED, __HIP_MEMORY_SCOPE_AGENT);
    asm volatile("s_waitcnt vmcnt(0)" ::: "memory");  // h acked (x prefetch long flown)
    __builtin_amdgcn_sched_barrier(0);
    if (lane == 0)
      __hip_atomic_fetch_add(ctr + ((size_t)(t + 1) * NG + bg) * 16, 1u,
                             __ATOMIC_RELAXED, __HIP_MEMORY_SCOPE_AGENT);

    // ---- o_t outputs off the critical path
    float2 ov = {o0, o1};
    *reinterpret_cast<float2*>(out + ((size_t)brow * T_ + t) * H_ + jc + j0) = ov;
    if (t == T_ - 1) {
      float2 hv = {h0, h1};
      *reinterpret_cast<float2*>(hT + (size_t)brow * H_ + jc + j0) = hv;
    }
  }
#undef LDX
#undef LDH
}

extern "C" void kernel_launch(void* const* d_in, const int* in_sizes, int n_in,
                              void* d_out, int out_size, void* d_ws, size_t ws_size,
                              hipStream_t stream) {
  const float* inputs = (const float*)d_in[0];
  const float* Wi = (const float*)d_in[1];
  const float* bi = (const float*)d_in[2];
  const float* Wh = (const float*)d_in[3];
  const float* bh = (const float*)d_in[4];
  float* out = (float*)d_out;
  float* hT = out + (size_t)B_ * T_ * H_;

  // workspace: [ctr 2049*256B = 524544][hbuf 2x64KB = 131072][xbf 128MB]
  unsigned int* ctr = (unsigned int*)d_ws;
  unsigned short* hbuf = (unsigned short*)((char*)d_ws + 524544);
  unsigned short* xbf = (unsigned short*)((char*)d_ws + 524544 + 131072);

  (void)hipFuncSetAttribute((const void*)lstm_kernel,
                            hipFuncAttributeMaxDynamicSharedMemorySize, 67584);

  prep_kernel<<<dim3(T_), dim3(256), 0, stream>>>(inputs, xbf, ctr);
  lstm_kernel<<<dim3(256), dim3(64), 67584, stream>>>(Wi, bi, Wh, bh, xbf, hbuf, ctr, out, hT);
}